// Round 7
// baseline (195.924 us; speedup 1.0000x reference)
//
#include <hip/hip_runtime.h>
#include <hip/hip_bf16.h>

// Causal attention, B=2 NH=16 T=2048 D=64, fp32 I/O.
// R7: BARRIER-FREE flash. S^T formulation; K fragments loaded fp32
// direct-to-register (cvt in-reg, no K prepass), V^T fragments loaded bf16
// direct-to-register (V^T prepass only). LDS used ONLY for the wave-private
// P round-trip (in-order DS pipe => no sync). Zero __syncthreads in fa_fwd.
// Grid 512, gid->iq permutation makes co-resident block pairs uniform
// (34 k64-tiles per CU).

typedef __bf16 bf16;
typedef __bf16 bf16x4 __attribute__((ext_vector_type(4)));
typedef __bf16 bf16x8 __attribute__((ext_vector_type(8)));
typedef float floatx4 __attribute__((ext_vector_type(4)));

#define T_SEQ 2048
#define DH 64
#define TQ 128
#define BHN 32
#define CEXP 0.18033688011112042f  // (1/sqrt(64)) * log2(e)

// ---------------- prepass: V [bh][T][64] fp32 -> V^T [bh][64][T] bf16 ----------------
__global__ __launch_bounds__(256) void prep(const float* __restrict__ V,
                                            bf16* __restrict__ Vt) {
    __shared__ bf16 tile[64][72];
    const int bid = (int)blockIdx.x;
    const int tid = (int)threadIdx.x;
    const int bh = bid & (BHN - 1);
    const int t0 = (bid >> 5) * 64;
    {
        const int r = tid >> 2;              // key row 0..63
        const int c = (tid & 3) * 16;        // dim col chunk
        const float* s = V + ((size_t)bh * T_SEQ + t0 + r) * DH + c;
        float4 f0 = *(const float4*)(s + 0);
        float4 f1 = *(const float4*)(s + 4);
        float4 f2 = *(const float4*)(s + 8);
        float4 f3 = *(const float4*)(s + 12);
        bf16x8 p0, p1;
        p0[0]=(bf16)f0.x; p0[1]=(bf16)f0.y; p0[2]=(bf16)f0.z; p0[3]=(bf16)f0.w;
        p0[4]=(bf16)f1.x; p0[5]=(bf16)f1.y; p0[6]=(bf16)f1.z; p0[7]=(bf16)f1.w;
        p1[0]=(bf16)f2.x; p1[1]=(bf16)f2.y; p1[2]=(bf16)f2.z; p1[3]=(bf16)f2.w;
        p1[4]=(bf16)f3.x; p1[5]=(bf16)f3.y; p1[6]=(bf16)f3.z; p1[7]=(bf16)f3.w;
        *(bf16x8*)&tile[r][c + 0] = p0;
        *(bf16x8*)&tile[r][c + 8] = p1;
    }
    __syncthreads();
    {
        const int d   = tid >> 2;            // dim 0..63
        const int tch = (tid & 3) * 16;      // 32B contiguous t-chunk per lane
        bf16x8 o0, o1;
        #pragma unroll
        for (int j = 0; j < 8; ++j) { o0[j] = tile[tch + j][d]; o1[j] = tile[tch + 8 + j][d]; }
        bf16* o = Vt + ((size_t)bh * DH + d) * T_SEQ + t0 + tch;
        *(bf16x8*)(o + 0) = o0;
        *(bf16x8*)(o + 8) = o1;
    }
}

// ---------------- main flash kernel: barrier-free ----------------
// MFMA 16x16x32: A[m=l16][k=quad*8+j], B[k=quad*8+j][n=l16],
// C/D col=l16, row=quad*4+reg.
// S^T[key][q] = K·Q^T: A = K rows direct from global fp32 (cvt in reg).
// O^T[d][q] = V^T·P^T: A = V^T rows direct from global bf16.
// P^T LDS round trip is wave-private (Pw): C-layout b64 writes -> B-frag
// b128 reads, XOR-swizzled (R5-proven formulas), in-order DS, no barrier.
__global__ __launch_bounds__(256, 4)
void fa_fwd(const float* __restrict__ Qg, const float* __restrict__ Kg,
            const bf16* __restrict__ Vt, float* __restrict__ Og)
{
    __shared__ __align__(16) bf16 smem[4][32 * 64];   // 4 KB per wave (P only)

    const int gid = (int)blockIdx.x;
    const int bh  = gid & (BHN - 1);
    const int j   = gid >> 5;                 // 0..15
    const int iq  = (j < 8) ? (15 - 2 * j) : (2 * j - 16);  // pairs (j,j+8) sum 15
    const int q0  = iq * TQ;

    const int tid  = (int)threadIdx.x;
    const int w4   = tid >> 6;
    const int lane = tid & 63;
    const int quad = lane >> 4;
    const int l16  = lane & 15;

    bf16* Pw = smem[w4];

    const float* Kbh = Kg + (size_t)bh * (T_SEQ * DH);
    const bf16*  Vbh = Vt + (size_t)bh * (DH * T_SEQ);
    const size_t qrb = (size_t)bh * T_SEQ;

    const int qw  = q0 + w4 * 32;             // this wave's 32 q columns
    const int nkt = (qw + 95) >> 6;           // per-wave causal k64-tile count

    // ---- Q as B-fragments (fp32 -> bf16 once) ----
    bf16x8 qb[2][2];
    #pragma unroll
    for (int nt = 0; nt < 2; ++nt) {
        const int qrow = qw + nt * 16 + l16;
        #pragma unroll
        for (int kk = 0; kk < 2; ++kk) {
            const float* s = Qg + (qrb + qrow) * DH + kk * 32 + quad * 8;
            float4 f0 = *(const float4*)(s);
            float4 f1 = *(const float4*)(s + 4);
            bf16x8 t;
            t[0]=(bf16)f0.x; t[1]=(bf16)f0.y; t[2]=(bf16)f0.z; t[3]=(bf16)f0.w;
            t[4]=(bf16)f1.x; t[5]=(bf16)f1.y; t[6]=(bf16)f1.z; t[7]=(bf16)f1.w;
            qb[nt][kk] = t;
        }
    }

    floatx4 oacc[4][2];
    #pragma unroll
    for (int mt = 0; mt < 4; ++mt)
        #pragma unroll
        for (int nt = 0; nt < 2; ++nt) oacc[mt][nt] = (floatx4){0.f,0.f,0.f,0.f};
    float lpart[2] = {0.f, 0.f};

    for (int kt = 0; kt < nkt; ++kt) {
        const int k0 = kt * 64;
        const bool domask = (k0 + 63 > qw);

        // ---- S^T = K·Q^T, per key-subtile: fp32 K direct load + cvt ----
        #pragma unroll
        for (int mt = 0; mt < 4; ++mt) {
            const float* kp = Kbh + (size_t)(k0 + mt * 16 + l16) * DH + quad * 8;
            float4 a0 = *(const float4*)(kp + 0);
            float4 a1 = *(const float4*)(kp + 4);
            float4 b0 = *(const float4*)(kp + 32);
            float4 b1 = *(const float4*)(kp + 36);
            bf16x8 kf0, kf1;
            kf0[0]=(bf16)a0.x; kf0[1]=(bf16)a0.y; kf0[2]=(bf16)a0.z; kf0[3]=(bf16)a0.w;
            kf0[4]=(bf16)a1.x; kf0[5]=(bf16)a1.y; kf0[6]=(bf16)a1.z; kf0[7]=(bf16)a1.w;
            kf1[0]=(bf16)b0.x; kf1[1]=(bf16)b0.y; kf1[2]=(bf16)b0.z; kf1[3]=(bf16)b0.w;
            kf1[4]=(bf16)b1.x; kf1[5]=(bf16)b1.y; kf1[6]=(bf16)b1.z; kf1[7]=(bf16)b1.w;

            floatx4 s0 = (floatx4){0.f,0.f,0.f,0.f};
            floatx4 s1 = (floatx4){0.f,0.f,0.f,0.f};
            s0 = __builtin_amdgcn_mfma_f32_16x16x32_bf16(kf0, qb[0][0], s0, 0, 0, 0);
            s0 = __builtin_amdgcn_mfma_f32_16x16x32_bf16(kf1, qb[0][1], s0, 0, 0, 0);
            s1 = __builtin_amdgcn_mfma_f32_16x16x32_bf16(kf0, qb[1][0], s1, 0, 0, 0);
            s1 = __builtin_amdgcn_mfma_f32_16x16x32_bf16(kf1, qb[1][1], s1, 0, 0, 0);

            if (domask) {
                #pragma unroll
                for (int r = 0; r < 4; ++r) {
                    const int keyg = k0 + mt * 16 + quad * 4 + r;
                    if (keyg > qw + l16)      s0[r] = -INFINITY;
                    if (keyg > qw + 16 + l16) s1[r] = -INFINITY;
                }
            }
            // exp + pack + P write (C-layout -> swizzled b64)
            bf16x4 w0, w1;
            #pragma unroll
            for (int r = 0; r < 4; ++r) {
                const float p0 = __builtin_amdgcn_exp2f(CEXP * s0[r]);
                const float p1 = __builtin_amdgcn_exp2f(CEXP * s1[r]);
                lpart[0] += p0; lpart[1] += p1;
                w0[r] = (bf16)p0; w1[r] = (bf16)p1;
            }
            const int r0 = l16;
            const int r1 = 16 + l16;
            const int c0 = (mt * 2 + (quad >> 1)) ^ (r0 & 7);
            const int c1 = (mt * 2 + (quad >> 1)) ^ (r1 & 7);
            *(bf16x4*)&Pw[r0 * 64 + c0 * 8 + (quad & 1) * 4] = w0;
            *(bf16x4*)&Pw[r1 * 64 + c1 * 8 + (quad & 1) * 4] = w1;
        }

        // ---- P^T B-fragments (wave-private, in-order DS) ----
        bf16x8 pf[2][2];
        #pragma unroll
        for (int nt = 0; nt < 2; ++nt) {
            const int row = nt * 16 + l16;
            #pragma unroll
            for (int kk = 0; kk < 2; ++kk)
                pf[nt][kk] = *(const bf16x8*)&Pw[row * 64 + (((kk * 4 + quad) ^ (row & 7)) * 8)];
        }

        // ---- O^T += V^T·P^T: V^T fragments direct from global bf16 ----
        #pragma unroll
        for (int mt = 0; mt < 4; ++mt) {
            const bf16* vp = Vbh + (size_t)(mt * 16 + l16) * T_SEQ + k0 + quad * 8;
            bf16x8 vf0 = *(const bf16x8*)(vp);
            bf16x8 vf1 = *(const bf16x8*)(vp + 32);
            oacc[mt][0] = __builtin_amdgcn_mfma_f32_16x16x32_bf16(vf0, pf[0][0], oacc[mt][0], 0, 0, 0);
            oacc[mt][0] = __builtin_amdgcn_mfma_f32_16x16x32_bf16(vf1, pf[0][1], oacc[mt][0], 0, 0, 0);
            oacc[mt][1] = __builtin_amdgcn_mfma_f32_16x16x32_bf16(vf0, pf[1][0], oacc[mt][1], 0, 0, 0);
            oacc[mt][1] = __builtin_amdgcn_mfma_f32_16x16x32_bf16(vf1, pf[1][1], oacc[mt][1], 0, 0, 0);
        }
    }

    // ---- epilogue: denominator reduce across quads, normalized store ----
    float invl[2];
    #pragma unroll
    for (int nt = 0; nt < 2; ++nt) {
        float v = lpart[nt];
        v += __shfl_xor(v, 16);
        v += __shfl_xor(v, 32);
        invl[nt] = 1.0f / v;
    }
    #pragma unroll
    for (int nt = 0; nt < 2; ++nt) {
        const size_t qrow = qrb + qw + nt * 16 + l16;
        #pragma unroll
        for (int mt = 0; mt < 4; ++mt) {
            float4 o;
            o.x = oacc[mt][nt][0] * invl[nt];
            o.y = oacc[mt][nt][1] * invl[nt];
            o.z = oacc[mt][nt][2] * invl[nt];
            o.w = oacc[mt][nt][3] * invl[nt];
            *(float4*)&Og[qrow * DH + mt * 16 + quad * 4] = o;
        }
    }
}

extern "C" void kernel_launch(void* const* d_in, const int* in_sizes, int n_in,
                              void* d_out, int out_size, void* d_ws, size_t ws_size,
                              hipStream_t stream) {
    const float* Q = (const float*)d_in[0];
    const float* K = (const float*)d_in[1];
    const float* V = (const float*)d_in[2];
    float* O = (float*)d_out;
    (void)in_sizes; (void)n_in; (void)out_size; (void)ws_size;

    bf16* Vtb = (bf16*)d_ws;   // 8 MiB V^T

    prep<<<dim3(1024), dim3(256), 0, stream>>>(V, Vtb);
    fa_fwd<<<dim3(512), dim3(256), 0, stream>>>(Q, K, Vtb, O);
}

// Round 8
// 155.946 us; speedup vs baseline: 1.2564x; 1.2564x over previous
//
#include <hip/hip_runtime.h>
#include <hip/hip_bf16.h>

// Causal attention, B=2 NH=16 T=2048 D=64, fp32 I/O.
// R8: R5 structure (512-thr, 2 k-groups x 4 waves, TK=64, DMA-staged LDS,
// grid 512 = 2 blocks/CU) + UNIFORM block durations:
//   chunk0 (gid>=256): heavy q-tile iq=15-p, group-steps 0..8   (9 steps)
//   chunk1 (gid<256) : heavy steps 9..15-p (7-p) -> write partial (bf16 O^T
//                      numerators + fp32 l) + release flag, then light tile
//                      iq=p, steps 0..p (p+1)                   (8 steps)
// chunk0 acquire-spins on the flag at its end (expected ~0 wait), adds the
// partial, finalizes heavy. All 512 blocks co-resident (2/CU) => safe.

typedef __bf16 bf16;
typedef __bf16 bf16x4 __attribute__((ext_vector_type(4)));
typedef __bf16 bf16x8 __attribute__((ext_vector_type(8)));
typedef float floatx4 __attribute__((ext_vector_type(4)));

#define T_SEQ 2048
#define DH 64
#define TQ 128
#define TK 64
#define BHN 32
#define CEXP 0.18033688011112042f  // (1/sqrt(64)) * log2(e)

__device__ __forceinline__ void gload16(const bf16* g, bf16* l) {
    __builtin_amdgcn_global_load_lds(
        (const __attribute__((address_space(1))) void*)g,
        (__attribute__((address_space(3))) void*)l, 16, 0, 0);
}

// ---------------- fused prepass ----------------
// bid [0,1024): K fp32 -> bf16 flat. bid [1024,2048): V -> V^T bf16.
// bid 2048: zero the 256 heavy-tile flags.
__global__ __launch_bounds__(256) void prep(const float* __restrict__ K,
                                            const float* __restrict__ V,
                                            bf16* __restrict__ Kb,
                                            bf16* __restrict__ Vt,
                                            int* __restrict__ flags) {
    const int bid = (int)blockIdx.x;
    const int tid = (int)threadIdx.x;
    if (bid == 2048) { if (tid < 256) flags[tid] = 0; return; }
    if (bid < 1024) {
        const size_t i = ((size_t)bid * 256 + tid) * 16;
        float4 a = *(const float4*)(K + i + 0);
        float4 b = *(const float4*)(K + i + 4);
        float4 c = *(const float4*)(K + i + 8);
        float4 d = *(const float4*)(K + i + 12);
        bf16x8 o0, o1;
        o0[0]=(bf16)a.x; o0[1]=(bf16)a.y; o0[2]=(bf16)a.z; o0[3]=(bf16)a.w;
        o0[4]=(bf16)b.x; o0[5]=(bf16)b.y; o0[6]=(bf16)b.z; o0[7]=(bf16)b.w;
        o1[0]=(bf16)c.x; o1[1]=(bf16)c.y; o1[2]=(bf16)c.z; o1[3]=(bf16)c.w;
        o1[4]=(bf16)d.x; o1[5]=(bf16)d.y; o1[6]=(bf16)d.z; o1[7]=(bf16)d.w;
        *(bf16x8*)(Kb + i + 0) = o0;
        *(bf16x8*)(Kb + i + 8) = o1;
        return;
    }
    __shared__ bf16 tile[64][72];
    const int vb = bid - 1024;
    const int bh = vb & (BHN - 1);
    const int t0 = (vb >> 5) * 64;
    {
        const int r = tid >> 2;
        const int c = (tid & 3) * 16;
        const float* s = V + ((size_t)bh * T_SEQ + t0 + r) * DH + c;
        float4 f0 = *(const float4*)(s + 0);
        float4 f1 = *(const float4*)(s + 4);
        float4 f2 = *(const float4*)(s + 8);
        float4 f3 = *(const float4*)(s + 12);
        bf16x8 p0, p1;
        p0[0]=(bf16)f0.x; p0[1]=(bf16)f0.y; p0[2]=(bf16)f0.z; p0[3]=(bf16)f0.w;
        p0[4]=(bf16)f1.x; p0[5]=(bf16)f1.y; p0[6]=(bf16)f1.z; p0[7]=(bf16)f1.w;
        p1[0]=(bf16)f2.x; p1[1]=(bf16)f2.y; p1[2]=(bf16)f2.z; p1[3]=(bf16)f2.w;
        p1[4]=(bf16)f3.x; p1[5]=(bf16)f3.y; p1[6]=(bf16)f3.z; p1[7]=(bf16)f3.w;
        *(bf16x8*)&tile[r][c + 0] = p0;
        *(bf16x8*)&tile[r][c + 8] = p1;
    }
    __syncthreads();
    {
        const int d   = tid >> 2;
        const int tch = (tid & 3) * 16;
        bf16x8 o0, o1;
        #pragma unroll
        for (int j = 0; j < 8; ++j) { o0[j] = tile[tch + j][d]; o1[j] = tile[tch + 8 + j][d]; }
        bf16* o = Vt + ((size_t)bh * DH + d) * T_SEQ + t0 + tch;
        *(bf16x8*)(o + 0) = o0;
        *(bf16x8*)(o + 8) = o1;
    }
}

// ---------------- main flash kernel ----------------
// LDS map (bf16): K[g]@g*4096, V[g]@8192+g*4096, P[w]@16384+w*2048 (64 KB).
// Combine scratch reuses bytes [0,32768) + P region (R5-proven).
__global__ __launch_bounds__(512, 4)
void fa_fwd(const float* __restrict__ Qg, const bf16* __restrict__ Kb,
            const bf16* __restrict__ Vt, float* __restrict__ Og,
            bf16* __restrict__ oblob, float* __restrict__ lblob,
            int* __restrict__ flags)
{
    __shared__ __align__(16) bf16 smem[32768];

    const int gid = (int)blockIdx.x;
    const bool isW = (gid < 256);          // chunk1 = writer (heavy tail + light)
    const int idx  = gid & 255;
    const int bh   = idx & (BHN - 1);
    const int p    = idx >> 5;             // 0..7
    const int q0h  = (15 - p) * TQ;
    const int q0l  = p * TQ;

    const int tid  = (int)threadIdx.x;
    const int wave = tid >> 6;
    const int w4   = wave & 3;
    const int g2   = wave >> 3 ? 1 : 0;    // placeholder; fixed below
    const int g2_  = wave >> 2;            // k-group 0/1
    (void)g2;
    const int grp  = g2_;
    const int lane = tid & 63;
    const int quad = lane >> 4;
    const int l16  = lane & 15;
    const int rl   = lane >> 3;
    const int gch  = (lane & 7) ^ rl;

    bf16* Ksh = smem + grp * 4096;
    bf16* Vsh = smem + 8192 + grp * 4096;
    bf16* Pw  = smem + 16384 + wave * 2048;

    const bf16* Kbh = Kb + (size_t)bh * (T_SEQ * DH);
    const bf16* Vbh = Vt + (size_t)bh * (DH * T_SEQ);
    const size_t qrb = (size_t)bh * T_SEQ;

    bf16*  ob = oblob + (((size_t)idx * 8 + wave) * 64 + lane) * 32;
    float* lb_ = lblob + (((size_t)idx * 8 + wave) * 64 + lane) * 2;
    int* flagp = flags + idx;

    bf16x8 qb[2][2];
    auto loadQ = [&](int qbase) {
        #pragma unroll
        for (int nt = 0; nt < 2; ++nt) {
            const int qrow = qbase + w4 * 32 + nt * 16 + l16;
            #pragma unroll
            for (int kk = 0; kk < 2; ++kk) {
                const float* s = Qg + (qrb + qrow) * DH + kk * 32 + quad * 8;
                float4 f0 = *(const float4*)(s);
                float4 f1 = *(const float4*)(s + 4);
                bf16x8 t;
                t[0]=(bf16)f0.x; t[1]=(bf16)f0.y; t[2]=(bf16)f0.z; t[3]=(bf16)f0.w;
                t[4]=(bf16)f1.x; t[5]=(bf16)f1.y; t[6]=(bf16)f1.z; t[7]=(bf16)f1.w;
                qb[nt][kk] = t;
            }
        }
    };

    floatx4 oacc[4][2];
    float lpart[2];
    auto resetAcc = [&]() {
        #pragma unroll
        for (int mt = 0; mt < 4; ++mt)
            #pragma unroll
            for (int nt = 0; nt < 2; ++nt) oacc[mt][nt] = (floatx4){0.f,0.f,0.f,0.f};
        lpart[0] = lpart[1] = 0.f;
    };

    // one group-superstep over k-tile kt = 2s+grp of the current q-range
    auto run_phase = [&](int qbase, int s0, int s1) {
        const int qw = qbase + w4 * 32;
        for (int s = s0; s < s1; ++s) {
            const int kt = 2 * s + grp;
            const int k0 = kt * TK;
            {
                const bf16* kg = Kbh + (size_t)kt * TK * DH;
                const bf16* vg = Vbh + kt * TK;
                #pragma unroll
                for (int g = 0; g < 2; ++g) {
                    const int row = w4 * 16 + g * 8;
                    gload16(kg + (size_t)(row + rl) * DH + gch * 8, &Ksh[row * DH]);
                    gload16(vg + (size_t)(row + rl) * T_SEQ + gch * 8, &Vsh[row * TK]);
                }
            }
            __syncthreads();

            #pragma unroll
            for (int mt = 0; mt < 4; ++mt) {
                floatx4 sv0 = (floatx4){0.f,0.f,0.f,0.f};
                floatx4 sv1 = (floatx4){0.f,0.f,0.f,0.f};
                const int R = mt * 16 + l16;
                #pragma unroll
                for (int kk = 0; kk < 2; ++kk) {
                    bf16x8 kf = *(const bf16x8*)&Ksh[R * DH + (((kk * 4 + quad) ^ (l16 & 7)) * 8)];
                    sv0 = __builtin_amdgcn_mfma_f32_16x16x32_bf16(kf, qb[0][kk], sv0, 0, 0, 0);
                    sv1 = __builtin_amdgcn_mfma_f32_16x16x32_bf16(kf, qb[1][kk], sv1, 0, 0, 0);
                }
                if (k0 + TK - 1 > qw) {
                    #pragma unroll
                    for (int r = 0; r < 4; ++r) {
                        const int keyg = k0 + mt * 16 + quad * 4 + r;
                        if (keyg > qw + l16)      sv0[r] = -INFINITY;
                        if (keyg > qw + 16 + l16) sv1[r] = -INFINITY;
                    }
                }
                bf16x4 w0, w1;
                #pragma unroll
                for (int r = 0; r < 4; ++r) {
                    const float p0 = __builtin_amdgcn_exp2f(CEXP * sv0[r]);
                    const float p1 = __builtin_amdgcn_exp2f(CEXP * sv1[r]);
                    lpart[0] += p0; lpart[1] += p1;
                    w0[r] = (bf16)p0; w1[r] = (bf16)p1;
                }
                const int r0 = l16, r1 = 16 + l16;
                const int c0 = (mt * 2 + (quad >> 1)) ^ (r0 & 7);
                const int c1 = (mt * 2 + (quad >> 1)) ^ (r1 & 7);
                *(bf16x4*)&Pw[r0 * TK + c0 * 8 + (quad & 1) * 4] = w0;
                *(bf16x4*)&Pw[r1 * TK + c1 * 8 + (quad & 1) * 4] = w1;
            }

            bf16x8 pf[2][2];
            #pragma unroll
            for (int nt = 0; nt < 2; ++nt) {
                const int row = nt * 16 + l16;
                #pragma unroll
                for (int kk = 0; kk < 2; ++kk)
                    pf[nt][kk] = *(const bf16x8*)&Pw[row * TK + (((kk * 4 + quad) ^ (row & 7)) * 8)];
            }
            #pragma unroll
            for (int kk = 0; kk < 2; ++kk) {
                #pragma unroll
                for (int mt = 0; mt < 4; ++mt) {
                    const int R = mt * 16 + l16;
                    bf16x8 vf = *(const bf16x8*)&Vsh[R * TK + (((kk * 4 + quad) ^ (l16 & 7)) * 8)];
                    oacc[mt][0] = __builtin_amdgcn_mfma_f32_16x16x32_bf16(vf, pf[0][kk], oacc[mt][0], 0, 0, 0);
                    oacc[mt][1] = __builtin_amdgcn_mfma_f32_16x16x32_bf16(vf, pf[1][kk], oacc[mt][1], 0, 0, 0);
                }
            }
            __syncthreads();
        }
    };

    // cross-group combine + normalized store for the current accumulators
    auto combineStore = [&](int qbase) {
        float* cb = (float*)smem + w4 * 2048;
        float* lbs = (float*)(smem + 16384) + w4 * 128;
        if (grp == 1) {
            #pragma unroll
            for (int mt = 0; mt < 4; ++mt)
                #pragma unroll
                for (int nt = 0; nt < 2; ++nt)
                    *(floatx4*)&cb[((mt * 2 + nt) * 64 + lane) * 4] = oacc[mt][nt];
            lbs[lane * 2 + 0] = lpart[0];
            lbs[lane * 2 + 1] = lpart[1];
        }
        __syncthreads();
        if (grp == 0) {
            lpart[0] += lbs[lane * 2 + 0];
            lpart[1] += lbs[lane * 2 + 1];
            float invl[2];
            #pragma unroll
            for (int nt = 0; nt < 2; ++nt) {
                float v = lpart[nt];
                v += __shfl_xor(v, 16);
                v += __shfl_xor(v, 32);
                invl[nt] = 1.0f / v;
            }
            #pragma unroll
            for (int nt = 0; nt < 2; ++nt) {
                const size_t qrow = qrb + qbase + w4 * 32 + nt * 16 + l16;
                #pragma unroll
                for (int mt = 0; mt < 4; ++mt) {
                    floatx4 obv = *(const floatx4*)&cb[((mt * 2 + nt) * 64 + lane) * 4];
                    float4 o;
                    o.x = (oacc[mt][nt][0] + obv[0]) * invl[nt];
                    o.y = (oacc[mt][nt][1] + obv[1]) * invl[nt];
                    o.z = (oacc[mt][nt][2] + obv[2]) * invl[nt];
                    o.w = (oacc[mt][nt][3] + obv[3]) * invl[nt];
                    *(float4*)&Og[qrow * DH + mt * 16 + quad * 4] = o;
                }
            }
        }
    };

    resetAcc();
    loadQ(q0h);

    if (isW) {
        // ---- chunk1: heavy tail s=9..15-p ----
        run_phase(q0h, 9, 16 - p);
        // write partial (bf16 numerators + fp32 l), release flag
        #pragma unroll
        for (int f2 = 0; f2 < 4; ++f2) {
            bf16x8 w;
            #pragma unroll
            for (int e = 0; e < 4; ++e) {
                w[e]     = (bf16)oacc[f2][0][e];      // frag (mt=f2, nt=0)
                w[4 + e] = (bf16)oacc[f2][1][e];      // frag (mt=f2, nt=1)
            }
            *(bf16x8*)(ob + f2 * 8) = w;
        }
        lb_[0] = lpart[0];
        lb_[1] = lpart[1];
        __syncthreads();                   // drains all waves' stores (vmcnt)
        if (tid == 0) {
            __threadfence();               // device-scope fence
            __hip_atomic_store(flagp, 1, __ATOMIC_RELEASE, __HIP_MEMORY_SCOPE_AGENT);
        }
        // ---- light tile ----
        resetAcc();
        loadQ(q0l);
        run_phase(q0l, 0, p + 1);
        combineStore(q0l);
    } else {
        // ---- chunk0: heavy head s=0..8 ----
        run_phase(q0h, 0, 9);
        // acquire partner's partial
        while (__hip_atomic_load(flagp, __ATOMIC_ACQUIRE, __HIP_MEMORY_SCOPE_AGENT) == 0)
            __builtin_amdgcn_s_sleep(8);
        #pragma unroll
        for (int f2 = 0; f2 < 4; ++f2) {
            bf16x8 w = *(const bf16x8*)(ob + f2 * 8);
            #pragma unroll
            for (int e = 0; e < 4; ++e) {
                oacc[f2][0][e] += (float)w[e];
                oacc[f2][1][e] += (float)w[4 + e];
            }
        }
        lpart[0] += lb_[0];
        lpart[1] += lb_[1];
        combineStore(q0h);
    }
}

extern "C" void kernel_launch(void* const* d_in, const int* in_sizes, int n_in,
                              void* d_out, int out_size, void* d_ws, size_t ws_size,
                              hipStream_t stream) {
    const float* Q = (const float*)d_in[0];
    const float* K = (const float*)d_in[1];
    const float* V = (const float*)d_in[2];
    float* O = (float*)d_out;
    (void)in_sizes; (void)n_in; (void)out_size; (void)ws_size;

    const size_t nelem = (size_t)BHN * T_SEQ * DH;   // 4,194,304
    bf16*  Kbf   = (bf16*)d_ws;                      // 8 MiB
    bf16*  Vtb   = Kbf + nelem;                      // 8 MiB
    bf16*  oblob = Vtb + nelem;                      // 256*8*64*32 bf16 = 8 MiB
    float* lblob = (float*)(oblob + (size_t)256 * 8 * 64 * 32);   // 1 MiB
    int*   flags = (int*)(lblob + (size_t)256 * 8 * 64 * 2);      // 1 KiB

    prep<<<dim3(2049), dim3(256), 0, stream>>>(K, V, Kbf, Vtb, flags);
    fa_fwd<<<dim3(512), dim3(512), 0, stream>>>(Q, Kbf, Vtb, O, oblob, lblob, flags);
}

// Round 9
// 122.746 us; speedup vs baseline: 1.5962x; 1.2705x over previous
//
#include <hip/hip_runtime.h>
#include <hip/hip_bf16.h>

// Causal attention, B=2 NH=16 T=2048 D=64, fp32 I/O.
// R9 = R5 (best, 44us) + R2's proven pipelining, enabled by TK=32:
//  - 512-thr block, 2 k-groups x 4 waves, TQ=128, heavy/light pairing (gid, gid+256)
//  - K and V^T double-buffered (TK=32 tiles), prefetch issued at superstep TOP,
//    ONE __syncthreads per superstep => DMA covered by ~800cyc of compute
//  - per-wave skip of fully-causal-masked tiles (saves ~10-15% DS/VALU)
//  - P round-trip: wave-private padded LDS (stride 40 elems, 2-way max = free)
//  - single 1024-block prep (K->bf16 + V->V^T), cuts prep-side launch cost

typedef __bf16 bf16;
typedef __bf16 bf16x4 __attribute__((ext_vector_type(4)));
typedef __bf16 bf16x8 __attribute__((ext_vector_type(8)));
typedef float floatx4 __attribute__((ext_vector_type(4)));

#define T_SEQ 2048
#define DH 64
#define TQ 128
#define TKS 32
#define BHN 32
#define CEXP 0.18033688011112042f  // (1/sqrt(64)) * log2(e)

__device__ __forceinline__ void gload16(const bf16* g, bf16* l) {
    __builtin_amdgcn_global_load_lds(
        (const __attribute__((address_space(1))) void*)g,
        (__attribute__((address_space(3))) void*)l, 16, 0, 0);
}

// ---------------- fused prepass, 1024 blocks ----------------
// bid [0,512): K fp32 -> bf16 flat, grid-stride x4.
// bid [512,1024): V -> V^T bf16, two 64x64 tiles per block.
__global__ __launch_bounds__(256) void prep(const float* __restrict__ K,
                                            const float* __restrict__ V,
                                            bf16* __restrict__ Kb,
                                            bf16* __restrict__ Vt) {
    const int bid = (int)blockIdx.x;
    const int tid = (int)threadIdx.x;
    if (bid < 512) {
        size_t i = ((size_t)bid * 256 + tid) * 8;
        #pragma unroll
        for (int it = 0; it < 4; ++it) {
            float4 a = *(const float4*)(K + i + 0);
            float4 b = *(const float4*)(K + i + 4);
            bf16x8 o;
            o[0]=(bf16)a.x; o[1]=(bf16)a.y; o[2]=(bf16)a.z; o[3]=(bf16)a.w;
            o[4]=(bf16)b.x; o[5]=(bf16)b.y; o[6]=(bf16)b.z; o[7]=(bf16)b.w;
            *(bf16x8*)(Kb + i) = o;
            i += (size_t)512 * 256 * 8;
        }
        return;
    }
    __shared__ bf16 tile[2][64][72];
    const int vb = bid - 512;                 // 0..511
    const int bh = vb & (BHN - 1);
    const int tp = (vb >> 5) * 128;           // pair of 64-row tiles
    #pragma unroll
    for (int tt = 0; tt < 2; ++tt) {
        const int r = tid >> 2;
        const int c = (tid & 3) * 16;
        const float* s = V + ((size_t)bh * T_SEQ + tp + tt * 64 + r) * DH + c;
        float4 f0 = *(const float4*)(s + 0);
        float4 f1 = *(const float4*)(s + 4);
        float4 f2 = *(const float4*)(s + 8);
        float4 f3 = *(const float4*)(s + 12);
        bf16x8 p0, p1;
        p0[0]=(bf16)f0.x; p0[1]=(bf16)f0.y; p0[2]=(bf16)f0.z; p0[3]=(bf16)f0.w;
        p0[4]=(bf16)f1.x; p0[5]=(bf16)f1.y; p0[6]=(bf16)f1.z; p0[7]=(bf16)f1.w;
        p1[0]=(bf16)f2.x; p1[1]=(bf16)f2.y; p1[2]=(bf16)f2.z; p1[3]=(bf16)f2.w;
        p1[4]=(bf16)f3.x; p1[5]=(bf16)f3.y; p1[6]=(bf16)f3.z; p1[7]=(bf16)f3.w;
        *(bf16x8*)&tile[tt][r][c + 0] = p0;
        *(bf16x8*)&tile[tt][r][c + 8] = p1;
    }
    __syncthreads();
    #pragma unroll
    for (int tt = 0; tt < 2; ++tt) {
        const int d   = tid >> 2;
        const int tch = (tid & 3) * 16;
        bf16x8 o0, o1;
        #pragma unroll
        for (int j = 0; j < 8; ++j) { o0[j] = tile[tt][tch + j][d]; o1[j] = tile[tt][tch + 8 + j][d]; }
        bf16* o = Vt + ((size_t)bh * DH + d) * T_SEQ + tp + tt * 64 + tch;
        *(bf16x8*)(o + 0) = o0;
        *(bf16x8*)(o + 8) = o1;
    }
}

// ---------------- main flash kernel ----------------
// LDS (bf16 elems, 26624 total = 52 KB):
//   K[g][buf] @ (g*2+buf)*2048   ([32 key][64 d], XOR-8 chunk swizzle)
//   V[g][buf] @ 8192+(g*2+buf)*2048 ([64 d][32 k], XOR-4 on (row>>1))
//   P[wave]   @ 16384+wave*1280  ([32 q][40] padded, no swizzle)
// Combine scratch reuses elems [0,16384) as float cb + P region as float lbs.
__global__ __launch_bounds__(512, 4)
void fa_fwd(const float* __restrict__ Qg, const bf16* __restrict__ Kb,
            const bf16* __restrict__ Vt, float* __restrict__ Og)
{
    __shared__ __align__(16) bf16 smem[26624];

    const int gid  = (int)blockIdx.x;
    const int half = gid >> 8;                // 0: heavy, 1: light
    const int idx  = gid & 255;
    const int bh   = idx & (BHN - 1);
    const int p_   = idx >> 5;                // 0..7
    const int iq   = half ? p_ : (15 - p_);
    const int q0   = iq * TQ;
    const int nsteps = 2 * iq + 2;            // per-group TK=32 supersteps

    const int tid  = (int)threadIdx.x;
    const int wave = tid >> 6;
    const int w4   = wave & 3;
    const int grp  = wave >> 2;               // k-group 0/1
    const int lane = tid & 63;
    const int quad = lane >> 4;
    const int l16  = lane & 15;

    bf16* Kbuf0 = smem + (grp * 2 + 0) * 2048;
    bf16* Kbuf1 = smem + (grp * 2 + 1) * 2048;
    bf16* Vbuf0 = smem + 8192 + (grp * 2 + 0) * 2048;
    bf16* Vbuf1 = smem + 8192 + (grp * 2 + 1) * 2048;
    bf16* Pw    = smem + 16384 + wave * 1280;

    const bf16* Kbh = Kb + (size_t)bh * (T_SEQ * DH);
    const bf16* Vbh = Vt + (size_t)bh * (DH * T_SEQ);
    const size_t qrb = (size_t)bh * T_SEQ;
    const int qw = q0 + w4 * 32;

    // staging lane constants (lane-linear LDS dest = base + lane*16B)
    const int krow = w4 * 8  + (lane >> 3);               // K tile row (key)
    const int kgch = (lane & 7) ^ ((lane >> 3) & 7);      // K global chunk
    const int vrow = w4 * 16 + (lane >> 2);               // V^T tile row (d)
    const int vgch = (lane & 3) ^ ((lane >> 3) & 3);      // V global chunk

    // ---- Q as B-fragments (registers) ----
    bf16x8 qb[2][2];
    #pragma unroll
    for (int nt = 0; nt < 2; ++nt) {
        const int qrow = qw + nt * 16 + l16;
        #pragma unroll
        for (int kk = 0; kk < 2; ++kk) {
            const float* s = Qg + (qrb + qrow) * DH + kk * 32 + quad * 8;
            float4 f0 = *(const float4*)(s);
            float4 f1 = *(const float4*)(s + 4);
            bf16x8 t;
            t[0]=(bf16)f0.x; t[1]=(bf16)f0.y; t[2]=(bf16)f0.z; t[3]=(bf16)f0.w;
            t[4]=(bf16)f1.x; t[5]=(bf16)f1.y; t[6]=(bf16)f1.z; t[7]=(bf16)f1.w;
            qb[nt][kk] = t;
        }
    }

    floatx4 oacc[4][2];
    #pragma unroll
    for (int mt = 0; mt < 4; ++mt)
        #pragma unroll
        for (int nt = 0; nt < 2; ++nt) oacc[mt][nt] = (floatx4){0.f,0.f,0.f,0.f};
    float lpart[2] = {0.f, 0.f};

    auto stage = [&](int kt, bf16* kb, bf16* vb) {
        const int k0 = kt * TKS;
        gload16(Kbh + (size_t)(k0 + krow) * DH + kgch * 8, kb + w4 * 512);
        gload16(Vbh + (size_t)vrow * T_SEQ + k0 + vgch * 8, vb + w4 * 512);
    };

    stage(grp, Kbuf0, Vbuf0);
    __syncthreads();                           // one-time exposed drain

    for (int s = 0; s < nsteps; ++s) {
        const int cur = s & 1;
        if (s + 1 < nsteps)                    // prefetch: in flight across compute
            stage(2 * (s + 1) + grp, cur ? Kbuf0 : Kbuf1, cur ? Vbuf0 : Vbuf1);

        const int kt = 2 * s + grp;
        const int k0 = kt * TKS;
        const bf16* Kcur = cur ? Kbuf1 : Kbuf0;
        const bf16* Vcur = cur ? Vbuf1 : Vbuf0;

        if (k0 <= qw + 31) {                   // skip fully-masked tiles (per wave)
            // ---- S^T = K · Q^T ----
            floatx4 sa[2][2];
            #pragma unroll
            for (int mt = 0; mt < 2; ++mt)
                #pragma unroll
                for (int nt = 0; nt < 2; ++nt) sa[mt][nt] = (floatx4){0.f,0.f,0.f,0.f};
            #pragma unroll
            for (int kk = 0; kk < 2; ++kk) {
                #pragma unroll
                for (int mt = 0; mt < 2; ++mt) {
                    bf16x8 kf = *(const bf16x8*)&Kcur[(mt * 16 + l16) * 64 + (((kk * 4 + quad) ^ (l16 & 7)) * 8)];
                    sa[mt][0] = __builtin_amdgcn_mfma_f32_16x16x32_bf16(kf, qb[0][kk], sa[mt][0], 0, 0, 0);
                    sa[mt][1] = __builtin_amdgcn_mfma_f32_16x16x32_bf16(kf, qb[1][kk], sa[mt][1], 0, 0, 0);
                }
            }
            // ---- causal mask (diagonal tiles) ----
            if (k0 + TKS - 1 > qw) {
                #pragma unroll
                for (int mt = 0; mt < 2; ++mt)
                    #pragma unroll
                    for (int nt = 0; nt < 2; ++nt) {
                        const int qg = qw + nt * 16 + l16;
                        #pragma unroll
                        for (int r = 0; r < 4; ++r) {
                            const int keyg = k0 + mt * 16 + quad * 4 + r;
                            if (keyg > qg) sa[mt][nt][r] = -INFINITY;
                        }
                    }
            }
            // ---- exp2 + P^T -> padded LDS (b64) ----
            #pragma unroll
            for (int mt = 0; mt < 2; ++mt)
                #pragma unroll
                for (int nt = 0; nt < 2; ++nt) {
                    bf16x4 w;
                    #pragma unroll
                    for (int r = 0; r < 4; ++r) {
                        const float pv = __builtin_amdgcn_exp2f(CEXP * sa[mt][nt][r]);
                        lpart[nt] += pv;
                        w[r] = (bf16)pv;
                    }
                    *(bf16x4*)&Pw[(nt * 16 + l16) * 40 + mt * 16 + quad * 4] = w;
                }
            // ---- P^T B-fragments (wave-private, in-order DS) ----
            bf16x8 pf[2];
            #pragma unroll
            for (int nt = 0; nt < 2; ++nt)
                pf[nt] = *(const bf16x8*)&Pw[(nt * 16 + l16) * 40 + quad * 8];
            // ---- O^T += V^T · P^T ----
            #pragma unroll
            for (int mt = 0; mt < 4; ++mt) {
                bf16x8 vf = *(const bf16x8*)&Vcur[(mt * 16 + l16) * 32 + ((quad ^ ((l16 >> 1) & 3)) * 8)];
                oacc[mt][0] = __builtin_amdgcn_mfma_f32_16x16x32_bf16(vf, pf[0], oacc[mt][0], 0, 0, 0);
                oacc[mt][1] = __builtin_amdgcn_mfma_f32_16x16x32_bf16(vf, pf[1], oacc[mt][1], 0, 0, 0);
            }
        }

        __syncthreads();   // releases cur for overwrite; drains prefetch DMA
    }

    // ---- cross-group combine through LDS (R5-proven) ----
    float* cb  = (float*)smem + w4 * 2048;          // reuses K+V regions (32 KB)
    float* lbs = (float*)(smem + 16384) + w4 * 128; // reuses P region
    if (grp == 1) {
        #pragma unroll
        for (int mt = 0; mt < 4; ++mt)
            #pragma unroll
            for (int nt = 0; nt < 2; ++nt)
                *(floatx4*)&cb[((mt * 2 + nt) * 64 + lane) * 4] = oacc[mt][nt];
        lbs[lane * 2 + 0] = lpart[0];
        lbs[lane * 2 + 1] = lpart[1];
    }
    __syncthreads();
    if (grp == 0) {
        lpart[0] += lbs[lane * 2 + 0];
        lpart[1] += lbs[lane * 2 + 1];
        float invl[2];
        #pragma unroll
        for (int nt = 0; nt < 2; ++nt) {
            float v = lpart[nt];
            v += __shfl_xor(v, 16);
            v += __shfl_xor(v, 32);
            invl[nt] = 1.0f / v;
        }
        #pragma unroll
        for (int nt = 0; nt < 2; ++nt) {
            const size_t qrow = qrb + qw + nt * 16 + l16;
            #pragma unroll
            for (int mt = 0; mt < 4; ++mt) {
                floatx4 ob = *(const floatx4*)&cb[((mt * 2 + nt) * 64 + lane) * 4];
                float4 o;
                o.x = (oacc[mt][nt][0] + ob[0]) * invl[nt];
                o.y = (oacc[mt][nt][1] + ob[1]) * invl[nt];
                o.z = (oacc[mt][nt][2] + ob[2]) * invl[nt];
                o.w = (oacc[mt][nt][3] + ob[3]) * invl[nt];
                *(float4*)&Og[qrow * DH + mt * 16 + quad * 4] = o;
            }
        }
    }
}

extern "C" void kernel_launch(void* const* d_in, const int* in_sizes, int n_in,
                              void* d_out, int out_size, void* d_ws, size_t ws_size,
                              hipStream_t stream) {
    const float* Q = (const float*)d_in[0];
    const float* K = (const float*)d_in[1];
    const float* V = (const float*)d_in[2];
    float* O = (float*)d_out;
    (void)in_sizes; (void)n_in; (void)out_size; (void)ws_size;

    const size_t nelem = (size_t)BHN * T_SEQ * DH;   // 4,194,304
    bf16* Kbf = (bf16*)d_ws;            // 8 MiB
    bf16* Vtb = Kbf + nelem;            // 8 MiB

    prep<<<dim3(1024), dim3(256), 0, stream>>>(K, V, Kbf, Vtb);
    fa_fwd<<<dim3(512), dim3(512), 0, stream>>>(Q, Kbf, Vtb, O);
}